// Round 7
// baseline (529.458 us; speedup 1.0000x reference)
//
#include <hip/hip_runtime.h>
#include <hip/hip_cooperative_groups.h>
#include <math.h>

namespace cg = cooperative_groups;

constexpr int N  = 50000;
constexpr int E  = 800000;
constexpr int F1 = 128;
constexpr int F2 = 16;
constexpr int BSHIFT  = 8;                        // 256-node buckets
constexpr int NBUCKET = (N + 255) >> BSHIFT;      // 196
constexpr int CHUNK   = 2048;                     // edges per scatter chunk
constexpr int CAP     = 6144;                     // per-bucket capacity
constexpr int SBLK    = (E + CHUNK - 1) / CHUNK;  // 391 scatter chunks
constexpr int TILES   = (N + 63) / 64;            // 782 gemm1 tiles
constexpr int GTILES  = (N + 15) / 16;            // 3125 gather1 tiles

typedef unsigned short ushort_t;
typedef unsigned char  uchar_t;
typedef __bf16 bf16x8 __attribute__((ext_vector_type(8)));
typedef float  f32x4  __attribute__((ext_vector_type(4)));

static __device__ __forceinline__ float blo(unsigned u) { return __uint_as_float(u << 16); }
static __device__ __forceinline__ float bhi(unsigned u) { return __uint_as_float(u & 0xffff0000u); }
static __device__ __forceinline__ ushort_t to_bf(float f) { __bf16 h = (__bf16)f; return *(ushort_t*)&h; }
static __device__ __forceinline__ uchar_t to_fp8(float f) {
    return (uchar_t)(__builtin_amdgcn_cvt_pk_fp8_f32(f, f, 0, false) & 0xff);
}
template <int S>
static __device__ __forceinline__ float cf8(unsigned u) {
    return __builtin_amdgcn_cvt_f32_fp8(u, S);
}

// exclusive scan over the 256 threads' values (4-wave shfl scan); sets tot.
// ALL 256 threads of the block must call (contains __syncthreads).
static __device__ __forceinline__ int excl_scan256(int v, int* wtot, int& tot) {
    int t = threadIdx.x;
    int lane = t & 63, wid = t >> 6;
    int incl = v;
#pragma unroll
    for (int d = 1; d < 64; d <<= 1) {
        int u = __shfl_up(incl, d, 64);
        if (lane >= d) incl += u;
    }
    if (lane == 63) wtot[wid] = incl;
    __syncthreads();
    int wb = 0;
    for (int w = 0; w < wid; ++w) wb += wtot[w];
    tot = wtot[0] + wtot[1] + wtot[2] + wtot[3];
    __syncthreads();   // wtot reusable after return
    return wb + incl - v;
}

__global__ __launch_bounds__(256, 4) void k_mega(
    const int* __restrict__ row, const int* __restrict__ col,
    const float* __restrict__ x, const float* __restrict__ W1,
    const float* __restrict__ b1, const float* __restrict__ W2,
    const float* __restrict__ b2,
    unsigned* __restrict__ P2, int* __restrict__ cnt_g, int* __restrict__ loff_g,
    ushort_t* __restrict__ csr16, int* __restrict__ seg_start,
    int* __restrict__ counts, float* __restrict__ dinv,
    uchar_t* __restrict__ h1q, ushort_t* __restrict__ h2s,
    float* __restrict__ out)
{
    __shared__ __align__(16) char smem[35072];
    cg::grid_group grid = cg::this_grid();
    int t   = threadIdx.x;
    int NBk = (int)gridDim.x;

    // ================= Phase 1: scatter (role A) || gemm1 (role B) =================
    int SC = min(SBLK, max(1, (NBk * 2) / 5));   // scatter-role block count
    if ((int)blockIdx.x < SC) {
        int* hist = (int*)smem;                  // [256]
        int* loff = hist + 256;                  // [256]
        int* lcur = loff + 256;                  // [256]
        int* wtot = lcur + 256;                  // [8]
        unsigned* eb = (unsigned*)(wtot + 8);    // [2048]
        for (int j = blockIdx.x; j < SBLK; j += SC) {
            hist[t] = 0;
            __syncthreads();
            int base = j * CHUNK;
            int ce[CHUNK / 256];
#pragma unroll
            for (int i = 0; i < CHUNK / 256; ++i) {
                int e = base + i * 256 + t;
                ce[i] = (e < E) ? col[e] : -1;
                if (ce[i] >= 0) atomicAdd(&hist[ce[i] >> BSHIFT], 1);
            }
            __syncthreads();
            int tot;
            int ex = excl_scan256(hist[t], wtot, tot);
            loff[t] = ex;
            lcur[t] = ex;
            if (t < NBUCKET) { cnt_g[t * SBLK + j] = hist[t]; loff_g[t * SBLK + j] = ex; }
            __syncthreads();
#pragma unroll
            for (int i = 0; i < CHUNK / 256; ++i) {   // LDS bucket-sort
                int e = base + i * 256 + t;
                if (ce[i] >= 0) {
                    int pos = atomicAdd(&lcur[ce[i] >> BSHIFT], 1);
                    eb[pos] = ((unsigned)row[e] << BSHIFT) | (unsigned)(ce[i] & 255);
                }
            }
            __syncthreads();
            int total = min(CHUNK, E - base);
#pragma unroll
            for (int i = 0; i < CHUNK / 256; ++i) {   // block-contiguous, fully coalesced
                int k = i * 256 + t;
                if (k < total) P2[base + k] = eb[k];
            }
            __syncthreads();
        }
    } else {
        // ---- gemm1 role: h1q = fp8(x @ W1), unscaled ----
        ushort_t* Wl = (ushort_t*)smem;          // [F1*136] bf16 W1^T
        {
            int n = t & 127, kh = t >> 7;
#pragma unroll
            for (int j = 0; j < 8; ++j) {
                int k0 = (kh * 8 + j) * 8;
                bf16x8 w;
#pragma unroll
                for (int i2 = 0; i2 < 8; ++i2) w[i2] = (__bf16)W1[(k0 + i2) * F1 + n];
                *(bf16x8*)&Wl[n * 136 + k0] = w;
            }
        }
        __syncthreads();
        int lane = t & 63, wv = t >> 6;
        int quad = lane >> 4, l15 = lane & 15;
        int gcount = NBk - SC;
#pragma unroll 1
        for (int tile = (int)blockIdx.x - SC; tile < TILES; tile += gcount) {
            int arow = tile * 64 + wv * 16 + l15;
            int rclamp = min(arow, N - 1);
            f32x4 acc[8] = {};
#pragma unroll
            for (int kk = 0; kk < 4; ++kk) {
                int k0 = kk * 32 + quad * 8;
                const float* xp = x + (size_t)rclamp * F1 + k0;
                float4 u0 = *(const float4*)xp;
                float4 u1 = *(const float4*)(xp + 4);
                bf16x8 a;
                a[0] = (__bf16)u0.x; a[1] = (__bf16)u0.y; a[2] = (__bf16)u0.z; a[3] = (__bf16)u0.w;
                a[4] = (__bf16)u1.x; a[5] = (__bf16)u1.y; a[6] = (__bf16)u1.z; a[7] = (__bf16)u1.w;
#pragma unroll
                for (int ct = 0; ct < 8; ++ct) {
                    bf16x8 bfr = *(const bf16x8*)&Wl[(ct * 16 + l15) * 136 + k0];
                    acc[ct] = __builtin_amdgcn_mfma_f32_16x16x32_bf16(a, bfr, acc[ct], 0, 0, 0);
                }
            }
            int orow0 = tile * 64 + wv * 16 + quad * 4;
#pragma unroll
            for (int r = 0; r < 4; ++r) {
                int orow = orow0 + r;
                if (orow < N) {
#pragma unroll
                    for (int ct = 0; ct < 8; ++ct)
                        h1q[(size_t)orow * F1 + ct * 16 + l15] = to_fp8(acc[ct][r]);
                }
            }
        }
    }
    __threadfence();
    grid.sync();

    // ================= Phase 2: binFinal (196 blocks active) =================
    if ((int)blockIdx.x < NBUCKET) {
        int b = blockIdx.x;
        int* cS    = (int*)smem;                 // [391]
        int* oS    = cS + SBLK;                  // [391]
        int* baseS = oS + SBLK;                  // [392]
        int* wtot2 = baseS + 392;                // [8]
        int* cnt   = wtot2 + 8;                  // [256]
        int* cur   = cnt + 256;                  // [256]
        unsigned* eb2 = (unsigned*)(cur + 256);  // [CAP]
        for (int jj = t; jj < SBLK; jj += 256) {
            cS[jj] = cnt_g[b * SBLK + jj];
            oS[jj] = loff_g[b * SBLK + jj];
        }
        cnt[t] = 0;
        __syncthreads();
        int tot0 = 0, tot1 = 0;
        int e0 = excl_scan256(cS[t], wtot2, tot0);
        baseS[t] = e0;
        int v1 = (256 + t < SBLK) ? cS[256 + t] : 0;
        int e1 = excl_scan256(v1, wtot2, tot1);
        if (256 + t < SBLK) baseS[256 + t] = tot0 + e1;
        int m = tot0 + tot1;
        __syncthreads();
        for (int k = t; k < m; k += 256) {       // segment gather + dest histogram
            int lo2 = 0, hi2 = SBLK - 1;
            while (lo2 < hi2) {
                int mid = (lo2 + hi2 + 1) >> 1;
                if (baseS[mid] <= k) lo2 = mid; else hi2 = mid - 1;
            }
            unsigned u = P2[lo2 * CHUNK + oS[lo2] + (k - baseS[lo2])];
            eb2[k] = u;
            atomicAdd(&cnt[u & 255], 1);
        }
        __syncthreads();
        int tot2;
        int exn = excl_scan256(cnt[t], wtot2, tot2);
        int o = b * CAP + exn;
        cur[t] = o;
        int lo = b << BSHIFT;
        int myc = cnt[t];
        if (lo + t < N) {
            seg_start[lo + t] = o;
            counts[lo + t]    = myc;
            dinv[lo + t]      = rsqrtf((float)myc + 1.f);
        }
        __syncthreads();
        for (int k = t; k < m; k += 256) {
            unsigned u = eb2[k];
            int pos = atomicAdd(&cur[u & 255], 1);
            csr16[pos] = (ushort_t)(u >> BSHIFT);
        }
    }
    __threadfence();
    grid.sync();

    // ================= Phase 3: gather1 (4 chains/wave) + fused gemm2 =================
    {
        ushort_t* W2l = (ushort_t*)smem;         // [F2*136]
        ushort_t* T   = W2l + F2 * 136;          // [16*136]
        float*    dv  = (float*)(T + 16 * 136);  // [16]
        for (int i = t; i < F1 * F2; i += 256) {
            int k = i >> 4, n = i & 15;
            W2l[n * 136 + k] = to_bf(W2[i]);
        }
        int lane = t & 63, wv = t >> 6;
        int g = lane >> 4, l15 = lane & 15;
        int gbase = lane & 48;
        float4 bL = ((const float4*)b1)[l15 * 2];
        float4 bH = ((const float4*)b1)[l15 * 2 + 1];

#define G1FLT(j_, jb_) { unsigned u = __shfl(pk, gbase + (jb_) + (j_));                     \
        e##j_ = __uint_as_float(u & 0xffff0000u);                                           \
        w##j_ = *(const uint2*)(h1q + ((size_t)(u & 0xffffu) << 7) + (l15 << 3)); }
#define G1ACC(j_) {                                                                         \
        a0 = fmaf(e##j_, cf8<0>(w##j_.x), a0); a1 = fmaf(e##j_, cf8<1>(w##j_.x), a1);       \
        a2 = fmaf(e##j_, cf8<2>(w##j_.x), a2); a3 = fmaf(e##j_, cf8<3>(w##j_.x), a3);       \
        a4 = fmaf(e##j_, cf8<0>(w##j_.y), a4); a5 = fmaf(e##j_, cf8<1>(w##j_.y), a5);       \
        a6 = fmaf(e##j_, cf8<2>(w##j_.y), a6); a7 = fmaf(e##j_, cf8<3>(w##j_.y), a7); }

#pragma unroll 1
        for (int tile = blockIdx.x; tile < GTILES; tile += NBk) {
            __syncthreads();   // W2l ready / previous tile's T consumed
            int nl = wv * 4 + g;
            int c = tile * 16 + nl;
            int cl = min(c, N - 1);
            float dc = 0.f;
            int s = seg_start[cl];
            int cnt3 = 0;
            if (c < N) { dc = dinv[c]; cnt3 = counts[c]; }
            uint2 wsf = *(const uint2*)(h1q + ((size_t)cl << 7) + (l15 << 3));
            int mcnt = cnt3;
            mcnt = max(mcnt, __shfl_xor(mcnt, 16));
            mcnt = max(mcnt, __shfl_xor(mcnt, 32));

            float a0 = 0.f, a1 = 0.f, a2 = 0.f, a3 = 0.f;
            float a4 = 0.f, a5 = 0.f, a6 = 0.f, a7 = 0.f;
            unsigned pk = 0;
            {
                int k = l15;
                if (k < cnt3) {
                    int r = csr16[s + k];
                    pk = ((unsigned)to_bf(dinv[r]) << 16) | (unsigned)r;
                }
            }
#pragma unroll 1
            for (int k0 = 0; k0 < mcnt; k0 += 16) {
                unsigned pknext = 0;
                {
                    int k = k0 + 16 + l15;
                    if (k < cnt3) {
                        int r = csr16[s + k];
                        pknext = ((unsigned)to_bf(dinv[r]) << 16) | (unsigned)r;
                    }
                }
                {
                    uint2 w0, w1, w2, w3, w4, w5, w6, w7;
                    float e0, e1, e2, e3, e4, e5, e6, e7;
                    G1FLT(0, 0) G1FLT(1, 0) G1FLT(2, 0) G1FLT(3, 0)
                    G1FLT(4, 0) G1FLT(5, 0) G1FLT(6, 0) G1FLT(7, 0)
                    G1ACC(0) G1ACC(1) G1ACC(2) G1ACC(3)
                    G1ACC(4) G1ACC(5) G1ACC(6) G1ACC(7)
                }
                if (k0 + 8 < mcnt) {
                    uint2 w0, w1, w2, w3, w4, w5, w6, w7;
                    float e0, e1, e2, e3, e4, e5, e6, e7;
                    G1FLT(0, 8) G1FLT(1, 8) G1FLT(2, 8) G1FLT(3, 8)
                    G1FLT(4, 8) G1FLT(5, 8) G1FLT(6, 8) G1FLT(7, 8)
                    G1ACC(0) G1ACC(1) G1ACC(2) G1ACC(3)
                    G1ACC(4) G1ACC(5) G1ACC(6) G1ACC(7)
                }
                pk = pknext;
            }
            {   // self term + bias + relu + pack -> T
                a0 = fmaf(dc, cf8<0>(wsf.x), a0); a1 = fmaf(dc, cf8<1>(wsf.x), a1);
                a2 = fmaf(dc, cf8<2>(wsf.x), a2); a3 = fmaf(dc, cf8<3>(wsf.x), a3);
                a4 = fmaf(dc, cf8<0>(wsf.y), a4); a5 = fmaf(dc, cf8<1>(wsf.y), a5);
                a6 = fmaf(dc, cf8<2>(wsf.y), a6); a7 = fmaf(dc, cf8<3>(wsf.y), a7);
                a0 = fmaxf(fmaf(dc, a0, bL.x), 0.f); a1 = fmaxf(fmaf(dc, a1, bL.y), 0.f);
                a2 = fmaxf(fmaf(dc, a2, bL.z), 0.f); a3 = fmaxf(fmaf(dc, a3, bL.w), 0.f);
                a4 = fmaxf(fmaf(dc, a4, bH.x), 0.f); a5 = fmaxf(fmaf(dc, a5, bH.y), 0.f);
                a6 = fmaxf(fmaf(dc, a6, bH.z), 0.f); a7 = fmaxf(fmaf(dc, a7, bH.w), 0.f);
                uint4 pp;
                pp.x = (unsigned)to_bf(a0) | ((unsigned)to_bf(a1) << 16);
                pp.y = (unsigned)to_bf(a2) | ((unsigned)to_bf(a3) << 16);
                pp.z = (unsigned)to_bf(a4) | ((unsigned)to_bf(a5) << 16);
                pp.w = (unsigned)to_bf(a6) | ((unsigned)to_bf(a7) << 16);
                *(uint4*)&T[nl * 136 + (l15 << 3)] = pp;
                if (l15 == 0) dv[nl] = dc;
            }
            __syncthreads();
            if (wv == 0) {   // 16x16: T(16x128) @ W2l^T(128x16)
                int quad = lane >> 4;
                f32x4 acc = {};
#pragma unroll
                for (int kk = 0; kk < 4; ++kk) {
                    int k0 = kk * 32 + quad * 8;
                    bf16x8 a = *(const bf16x8*)&T[l15 * 136 + k0];
                    bf16x8 bfr = *(const bf16x8*)&W2l[l15 * 136 + k0];
                    acc = __builtin_amdgcn_mfma_f32_16x16x32_bf16(a, bfr, acc, 0, 0, 0);
                }
#pragma unroll
                for (int r = 0; r < 4; ++r) {
                    int rw = quad * 4 + r;
                    int gn = tile * 16 + rw;
                    if (gn < N) h2s[(size_t)gn * F2 + l15] = to_bf(acc[r] * dv[rw]);
                }
            }
        }
#undef G1FLT
#undef G1ACC
    }
    __threadfence();
    grid.sync();

    // ================= Phase 4: gather2 + log_softmax (8 lanes/node) =================
    {
        int lane = t & 63;
        int gb = lane & 56;
#pragma unroll 1
        for (int idx = (int)blockIdx.x * 256 + t; idx < N * 8; idx += NBk * 256) {
            int node = idx >> 3, sub = idx & 7;
            int s = seg_start[node], cntc = counts[node];
            float dc = dinv[node];
            float2 bb = ((const float2*)b2)[sub];
            unsigned us = ((const unsigned*)(h2s + (size_t)node * F2))[sub];
            float ax = 0.f, ay = 0.f;

#define G2LOAD(n_) { int src = gb | min(n_, rem - 1); int r = __shfl(rl, src);              \
        w##n_ = ((const unsigned*)(h2s + (size_t)r * F2))[sub]; if (n_ >= rem) w##n_ = 0u; }

            int rl = 0;
            if (sub < min(cntc, 8)) rl = csr16[s + sub];
#pragma unroll 1
            for (int j0 = 0; j0 < cntc; j0 += 8) {
                int rem = min(cntc - j0, 8);
                int rlnext = 0;
                int j2 = j0 + 8;
                if (j2 < cntc && sub < cntc - j2) rlnext = csr16[s + j2 + sub];
                unsigned w0, w1, w2, w3, w4, w5, w6, w7;
                G2LOAD(0) G2LOAD(1) G2LOAD(2) G2LOAD(3)
                G2LOAD(4) G2LOAD(5) G2LOAD(6) G2LOAD(7)
                ax += ((blo(w0) + blo(w1)) + (blo(w2) + blo(w3))) +
                      ((blo(w4) + blo(w5)) + (blo(w6) + blo(w7)));
                ay += ((bhi(w0) + bhi(w1)) + (bhi(w2) + bhi(w3))) +
                      ((bhi(w4) + bhi(w5)) + (bhi(w6) + bhi(w7)));
                rl = rlnext;
            }
#undef G2LOAD
            ax += blo(us);
            ay += bhi(us);
            float v0 = fmaf(dc, ax, bb.x);
            float v1 = fmaf(dc, ay, bb.y);
            float mx = fmaxf(v0, v1);
#pragma unroll
            for (int mm = 1; mm < 8; mm <<= 1) mx = fmaxf(mx, __shfl_xor(mx, mm));
            float sm = expf(v0 - mx) + expf(v1 - mx);
#pragma unroll
            for (int mm = 1; mm < 8; mm <<= 1) sm += __shfl_xor(sm, mm);
            float lse = mx + logf(sm);
            float2 o;
            o.x = v0 - lse;
            o.y = v1 - lse;
            ((float2*)(out + (size_t)node * F2))[sub] = o;
        }
    }
}

extern "C" void kernel_launch(void* const* d_in, const int* in_sizes, int n_in,
                              void* d_out, int out_size, void* d_ws, size_t ws_size,
                              hipStream_t stream) {
    const float* x  = (const float*)d_in[0];
    const int*   ei = (const int*)d_in[1];
    const float* W1 = (const float*)d_in[2];
    const float* b1 = (const float*)d_in[3];
    const float* W2 = (const float*)d_in[4];
    const float* b2 = (const float*)d_in[5];
    const int* rowp = ei;
    const int* colp = ei + E;

    char* ws = (char*)d_ws;
    unsigned* P2        = (unsigned*)ws; ws += (size_t)SBLK * CHUNK * 4;    // 3.2 MB
    int*      cnt_g     = (int*)ws;      ws += (size_t)NBUCKET * SBLK * 4;  // 306 KB
    int*      loff_g    = (int*)ws;      ws += (size_t)NBUCKET * SBLK * 4;  // 306 KB
    ushort_t* csr16     = (ushort_t*)ws; ws += (size_t)NBUCKET * CAP * 2;   // 2.4 MB
    int*      seg_start = (int*)ws;      ws += (size_t)N * 4;
    int*      counts    = (int*)ws;      ws += (size_t)N * 4;
    float*    dinvp     = (float*)ws;    ws += (size_t)N * 4;
    uchar_t*  h1q       = (uchar_t*)ws;  ws += (size_t)N * F1;              // 6.4 MB
    ushort_t* h2s       = (ushort_t*)ws; ws += (size_t)N * F2 * 2;          // 1.6 MB
    float*    outp      = (float*)d_out;

    static int NB = 0;
    if (NB == 0) {
        int mbs = 0;
        (void)hipOccupancyMaxActiveBlocksPerMultiprocessor(&mbs, k_mega, 256, 0);
        if (mbs < 1) mbs = 1;
        long nb = (long)mbs * 256;   // 256 CUs on MI355X
        NB = (int)(nb > 1024 ? 1024 : nb);
        if (NB < 256) NB = 256;
    }

    void* args[] = { (void*)&rowp, (void*)&colp, (void*)&x, (void*)&W1, (void*)&b1,
                     (void*)&W2, (void*)&b2, (void*)&P2, (void*)&cnt_g, (void*)&loff_g,
                     (void*)&csr16, (void*)&seg_start, (void*)&counts, (void*)&dinvp,
                     (void*)&h1q, (void*)&h2s, (void*)&outp };
    (void)hipLaunchCooperativeKernel((const void*)k_mega, dim3(NB), dim3(256),
                                     args, 0, stream);
}

// Round 8
// 380.378 us; speedup vs baseline: 1.3919x; 1.3919x over previous
//
#include <hip/hip_runtime.h>
#include <hip/hip_cooperative_groups.h>
#include <math.h>

namespace cg = cooperative_groups;

constexpr int N  = 50000;
constexpr int E  = 800000;
constexpr int F1 = 128;
constexpr int F2 = 16;
constexpr int BSHIFT  = 8;                        // 256-node buckets
constexpr int NBUCKET = (N + 255) >> BSHIFT;      // 196
constexpr int CHUNK   = 2048;                     // edges per scatter chunk
constexpr int CAP     = 6144;                     // per-bucket capacity
constexpr int SBLK    = (E + CHUNK - 1) / CHUNK;  // 391 scatter chunks
constexpr int TILES   = (N + 63) / 64;            // 782 gemm1 tiles
constexpr int GTILES  = (N + 15) / 16;            // 3125 gather1 tiles

typedef unsigned short ushort_t;
typedef unsigned char  uchar_t;
typedef __bf16 bf16x8 __attribute__((ext_vector_type(8)));
typedef float  f32x4  __attribute__((ext_vector_type(4)));

static __device__ __forceinline__ float blo(unsigned u) { return __uint_as_float(u << 16); }
static __device__ __forceinline__ float bhi(unsigned u) { return __uint_as_float(u & 0xffff0000u); }
static __device__ __forceinline__ ushort_t to_bf(float f) { __bf16 h = (__bf16)f; return *(ushort_t*)&h; }
static __device__ __forceinline__ uchar_t to_fp8(float f) {
    return (uchar_t)(__builtin_amdgcn_cvt_pk_fp8_f32(f, f, 0, false) & 0xff);
}
template <int S>
static __device__ __forceinline__ float cf8(unsigned u) {
    return __builtin_amdgcn_cvt_f32_fp8(u, S);
}

// exclusive scan over the 256 threads' values (4-wave shfl scan); sets tot.
// ALL 256 threads of the block must call (contains __syncthreads).
static __device__ __forceinline__ int excl_scan256(int v, int* wtot, int& tot) {
    int t = threadIdx.x;
    int lane = t & 63, wid = t >> 6;
    int incl = v;
#pragma unroll
    for (int d = 1; d < 64; d <<= 1) {
        int u = __shfl_up(incl, d, 64);
        if (lane >= d) incl += u;
    }
    if (lane == 63) wtot[wid] = incl;
    __syncthreads();
    int wb = 0;
    for (int w = 0; w < wid; ++w) wb += wtot[w];
    tot = wtot[0] + wtot[1] + wtot[2] + wtot[3];
    __syncthreads();   // wtot reusable after return
    return wb + incl - v;
}

// launch_bounds: min-waves/EU = 2 (VGPR cap ~256). Round 7's (256,4) capped VGPR at 64
// -> massive scratch spill (FETCH+WRITE inflated ~90MB, 750us). LDS (35KB) caps
// residency at 4 blocks/CU regardless, so the ,4 bought nothing.
__global__ __launch_bounds__(256, 2) void k_mega(
    const int* __restrict__ row, const int* __restrict__ col,
    const float* __restrict__ x, const float* __restrict__ W1,
    const float* __restrict__ b1, const float* __restrict__ W2,
    const float* __restrict__ b2,
    unsigned* __restrict__ P2, int* __restrict__ cnt_g, int* __restrict__ loff_g,
    ushort_t* __restrict__ csr16, int* __restrict__ seg_start,
    int* __restrict__ counts, float* __restrict__ dinv,
    uchar_t* __restrict__ h1q, ushort_t* __restrict__ h2s,
    float* __restrict__ out)
{
    __shared__ __align__(16) char smem[35072];
    cg::grid_group grid = cg::this_grid();
    int t   = threadIdx.x;
    int NBk = (int)gridDim.x;

    // ================= Phase 1: scatter (role A) || gemm1 (role B) =================
    int SC = min(SBLK, max(1, (NBk * 2) / 5));   // scatter-role block count
    if ((int)blockIdx.x < SC) {
        int* hist = (int*)smem;                  // [256]
        int* loff = hist + 256;                  // [256]
        int* lcur = loff + 256;                  // [256]
        int* wtot = lcur + 256;                  // [8]
        unsigned* eb = (unsigned*)(wtot + 8);    // [2048]
        for (int j = blockIdx.x; j < SBLK; j += SC) {
            hist[t] = 0;
            __syncthreads();
            int base = j * CHUNK;
            int ce[CHUNK / 256];
#pragma unroll
            for (int i = 0; i < CHUNK / 256; ++i) {
                int e = base + i * 256 + t;
                ce[i] = (e < E) ? col[e] : -1;
                if (ce[i] >= 0) atomicAdd(&hist[ce[i] >> BSHIFT], 1);
            }
            __syncthreads();
            int tot;
            int ex = excl_scan256(hist[t], wtot, tot);
            loff[t] = ex;
            lcur[t] = ex;
            if (t < NBUCKET) { cnt_g[t * SBLK + j] = hist[t]; loff_g[t * SBLK + j] = ex; }
            __syncthreads();
#pragma unroll
            for (int i = 0; i < CHUNK / 256; ++i) {   // LDS bucket-sort
                int e = base + i * 256 + t;
                if (ce[i] >= 0) {
                    int pos = atomicAdd(&lcur[ce[i] >> BSHIFT], 1);
                    eb[pos] = ((unsigned)row[e] << BSHIFT) | (unsigned)(ce[i] & 255);
                }
            }
            __syncthreads();
            int total = min(CHUNK, E - base);
#pragma unroll
            for (int i = 0; i < CHUNK / 256; ++i) {   // block-contiguous, fully coalesced
                int k = i * 256 + t;
                if (k < total) P2[base + k] = eb[k];
            }
            __syncthreads();
        }
    } else {
        // ---- gemm1 role: h1q = fp8(x @ W1), unscaled ----
        ushort_t* Wl = (ushort_t*)smem;          // [F1*136] bf16 W1^T
        {
            int n = t & 127, kh = t >> 7;
#pragma unroll
            for (int j = 0; j < 8; ++j) {
                int k0 = (kh * 8 + j) * 8;
                bf16x8 w;
#pragma unroll
                for (int i2 = 0; i2 < 8; ++i2) w[i2] = (__bf16)W1[(k0 + i2) * F1 + n];
                *(bf16x8*)&Wl[n * 136 + k0] = w;
            }
        }
        __syncthreads();
        int lane = t & 63, wv = t >> 6;
        int quad = lane >> 4, l15 = lane & 15;
        int gcount = NBk - SC;
#pragma unroll 1
        for (int tile = (int)blockIdx.x - SC; tile < TILES; tile += gcount) {
            int arow = tile * 64 + wv * 16 + l15;
            int rclamp = min(arow, N - 1);
            f32x4 acc[8] = {};
#pragma unroll
            for (int kk = 0; kk < 4; ++kk) {
                int k0 = kk * 32 + quad * 8;
                const float* xp = x + (size_t)rclamp * F1 + k0;
                float4 u0 = *(const float4*)xp;
                float4 u1 = *(const float4*)(xp + 4);
                bf16x8 a;
                a[0] = (__bf16)u0.x; a[1] = (__bf16)u0.y; a[2] = (__bf16)u0.z; a[3] = (__bf16)u0.w;
                a[4] = (__bf16)u1.x; a[5] = (__bf16)u1.y; a[6] = (__bf16)u1.z; a[7] = (__bf16)u1.w;
#pragma unroll
                for (int ct = 0; ct < 8; ++ct) {
                    bf16x8 bfr = *(const bf16x8*)&Wl[(ct * 16 + l15) * 136 + k0];
                    acc[ct] = __builtin_amdgcn_mfma_f32_16x16x32_bf16(a, bfr, acc[ct], 0, 0, 0);
                }
            }
            int orow0 = tile * 64 + wv * 16 + quad * 4;
#pragma unroll
            for (int r = 0; r < 4; ++r) {
                int orow = orow0 + r;
                if (orow < N) {
#pragma unroll
                    for (int ct = 0; ct < 8; ++ct)
                        h1q[(size_t)orow * F1 + ct * 16 + l15] = to_fp8(acc[ct][r]);
                }
            }
        }
    }
    __threadfence();
    grid.sync();

    // ================= Phase 2: binFinal (196 blocks active) =================
    if ((int)blockIdx.x < NBUCKET) {
        int b = blockIdx.x;
        int* cS    = (int*)smem;                 // [391]
        int* oS    = cS + SBLK;                  // [391]
        int* baseS = oS + SBLK;                  // [392]
        int* wtot2 = baseS + 392;                // [8]
        int* cnt   = wtot2 + 8;                  // [256]
        int* cur   = cnt + 256;                  // [256]
        unsigned* eb2 = (unsigned*)(cur + 256);  // [CAP]
        for (int jj = t; jj < SBLK; jj += 256) {
            cS[jj] = cnt_g[b * SBLK + jj];
            oS[jj] = loff_g[b * SBLK + jj];
        }
        cnt[t] = 0;
        __syncthreads();
        int tot0 = 0, tot1 = 0;
        int e0 = excl_scan256(cS[t], wtot2, tot0);
        baseS[t] = e0;
        int v1 = (256 + t < SBLK) ? cS[256 + t] : 0;
        int e1 = excl_scan256(v1, wtot2, tot1);
        if (256 + t < SBLK) baseS[256 + t] = tot0 + e1;
        int m = tot0 + tot1;
        __syncthreads();
        for (int k = t; k < m; k += 256) {       // segment gather + dest histogram
            int lo2 = 0, hi2 = SBLK - 1;
            while (lo2 < hi2) {
                int mid = (lo2 + hi2 + 1) >> 1;
                if (baseS[mid] <= k) lo2 = mid; else hi2 = mid - 1;
            }
            unsigned u = P2[lo2 * CHUNK + oS[lo2] + (k - baseS[lo2])];
            eb2[k] = u;
            atomicAdd(&cnt[u & 255], 1);
        }
        __syncthreads();
        int tot2;
        int exn = excl_scan256(cnt[t], wtot2, tot2);
        int o = b * CAP + exn;
        cur[t] = o;
        int lo = b << BSHIFT;
        int myc = cnt[t];
        if (lo + t < N) {
            seg_start[lo + t] = o;
            counts[lo + t]    = myc;
            dinv[lo + t]      = rsqrtf((float)myc + 1.f);
        }
        __syncthreads();
        for (int k = t; k < m; k += 256) {
            unsigned u = eb2[k];
            int pos = atomicAdd(&cur[u & 255], 1);
            csr16[pos] = (ushort_t)(u >> BSHIFT);
        }
    }
    __threadfence();
    grid.sync();

    // ================= Phase 3: gather1 (4 chains/wave) + fused gemm2 =================
    {
        ushort_t* W2l = (ushort_t*)smem;         // [F2*136]
        ushort_t* T   = W2l + F2 * 136;          // [16*136]
        float*    dv  = (float*)(T + 16 * 136);  // [16]
        for (int i = t; i < F1 * F2; i += 256) {
            int k = i >> 4, n = i & 15;
            W2l[n * 136 + k] = to_bf(W2[i]);
        }
        int lane = t & 63, wv = t >> 6;
        int g = lane >> 4, l15 = lane & 15;
        int gbase = lane & 48;
        float4 bL = ((const float4*)b1)[l15 * 2];
        float4 bH = ((const float4*)b1)[l15 * 2 + 1];

#define G1FLT(j_, jb_) { unsigned u = __shfl(pk, gbase + (jb_) + (j_));                     \
        e##j_ = __uint_as_float(u & 0xffff0000u);                                           \
        w##j_ = *(const uint2*)(h1q + ((size_t)(u & 0xffffu) << 7) + (l15 << 3)); }
#define G1ACC(j_) {                                                                         \
        a0 = fmaf(e##j_, cf8<0>(w##j_.x), a0); a1 = fmaf(e##j_, cf8<1>(w##j_.x), a1);       \
        a2 = fmaf(e##j_, cf8<2>(w##j_.x), a2); a3 = fmaf(e##j_, cf8<3>(w##j_.x), a3);       \
        a4 = fmaf(e##j_, cf8<0>(w##j_.y), a4); a5 = fmaf(e##j_, cf8<1>(w##j_.y), a5);       \
        a6 = fmaf(e##j_, cf8<2>(w##j_.y), a6); a7 = fmaf(e##j_, cf8<3>(w##j_.y), a7); }

#pragma unroll 1
        for (int tile = blockIdx.x; tile < GTILES; tile += NBk) {
            __syncthreads();   // W2l ready / previous tile's T consumed
            int nl = wv * 4 + g;
            int c = tile * 16 + nl;
            int cl = min(c, N - 1);
            float dc = 0.f;
            int s = seg_start[cl];
            int cnt3 = 0;
            if (c < N) { dc = dinv[c]; cnt3 = counts[c]; }
            uint2 wsf = *(const uint2*)(h1q + ((size_t)cl << 7) + (l15 << 3));
            int mcnt = cnt3;
            mcnt = max(mcnt, __shfl_xor(mcnt, 16));
            mcnt = max(mcnt, __shfl_xor(mcnt, 32));

            float a0 = 0.f, a1 = 0.f, a2 = 0.f, a3 = 0.f;
            float a4 = 0.f, a5 = 0.f, a6 = 0.f, a7 = 0.f;
            unsigned pk = 0;
            {
                int k = l15;
                if (k < cnt3) {
                    int r = csr16[s + k];
                    pk = ((unsigned)to_bf(dinv[r]) << 16) | (unsigned)r;
                }
            }
#pragma unroll 1
            for (int k0 = 0; k0 < mcnt; k0 += 16) {
                unsigned pknext = 0;
                {
                    int k = k0 + 16 + l15;
                    if (k < cnt3) {
                        int r = csr16[s + k];
                        pknext = ((unsigned)to_bf(dinv[r]) << 16) | (unsigned)r;
                    }
                }
                {
                    uint2 w0, w1, w2, w3, w4, w5, w6, w7;
                    float e0, e1, e2, e3, e4, e5, e6, e7;
                    G1FLT(0, 0) G1FLT(1, 0) G1FLT(2, 0) G1FLT(3, 0)
                    G1FLT(4, 0) G1FLT(5, 0) G1FLT(6, 0) G1FLT(7, 0)
                    G1ACC(0) G1ACC(1) G1ACC(2) G1ACC(3)
                    G1ACC(4) G1ACC(5) G1ACC(6) G1ACC(7)
                }
                if (k0 + 8 < mcnt) {
                    uint2 w0, w1, w2, w3, w4, w5, w6, w7;
                    float e0, e1, e2, e3, e4, e5, e6, e7;
                    G1FLT(0, 8) G1FLT(1, 8) G1FLT(2, 8) G1FLT(3, 8)
                    G1FLT(4, 8) G1FLT(5, 8) G1FLT(6, 8) G1FLT(7, 8)
                    G1ACC(0) G1ACC(1) G1ACC(2) G1ACC(3)
                    G1ACC(4) G1ACC(5) G1ACC(6) G1ACC(7)
                }
                pk = pknext;
            }
            {   // self term + bias + relu + pack -> T
                a0 = fmaf(dc, cf8<0>(wsf.x), a0); a1 = fmaf(dc, cf8<1>(wsf.x), a1);
                a2 = fmaf(dc, cf8<2>(wsf.x), a2); a3 = fmaf(dc, cf8<3>(wsf.x), a3);
                a4 = fmaf(dc, cf8<0>(wsf.y), a4); a5 = fmaf(dc, cf8<1>(wsf.y), a5);
                a6 = fmaf(dc, cf8<2>(wsf.y), a6); a7 = fmaf(dc, cf8<3>(wsf.y), a7);
                a0 = fmaxf(fmaf(dc, a0, bL.x), 0.f); a1 = fmaxf(fmaf(dc, a1, bL.y), 0.f);
                a2 = fmaxf(fmaf(dc, a2, bL.z), 0.f); a3 = fmaxf(fmaf(dc, a3, bL.w), 0.f);
                a4 = fmaxf(fmaf(dc, a4, bH.x), 0.f); a5 = fmaxf(fmaf(dc, a5, bH.y), 0.f);
                a6 = fmaxf(fmaf(dc, a6, bH.z), 0.f); a7 = fmaxf(fmaf(dc, a7, bH.w), 0.f);
                uint4 pp;
                pp.x = (unsigned)to_bf(a0) | ((unsigned)to_bf(a1) << 16);
                pp.y = (unsigned)to_bf(a2) | ((unsigned)to_bf(a3) << 16);
                pp.z = (unsigned)to_bf(a4) | ((unsigned)to_bf(a5) << 16);
                pp.w = (unsigned)to_bf(a6) | ((unsigned)to_bf(a7) << 16);
                *(uint4*)&T[nl * 136 + (l15 << 3)] = pp;
                if (l15 == 0) dv[nl] = dc;
            }
            __syncthreads();
            if (wv == 0) {   // 16x16: T(16x128) @ W2l^T(128x16)
                int quad = lane >> 4;
                f32x4 acc = {};
#pragma unroll
                for (int kk = 0; kk < 4; ++kk) {
                    int k0 = kk * 32 + quad * 8;
                    bf16x8 a = *(const bf16x8*)&T[l15 * 136 + k0];
                    bf16x8 bfr = *(const bf16x8*)&W2l[l15 * 136 + k0];
                    acc = __builtin_amdgcn_mfma_f32_16x16x32_bf16(a, bfr, acc, 0, 0, 0);
                }
#pragma unroll
                for (int r = 0; r < 4; ++r) {
                    int rw = quad * 4 + r;
                    int gn = tile * 16 + rw;
                    if (gn < N) h2s[(size_t)gn * F2 + l15] = to_bf(acc[r] * dv[rw]);
                }
            }
        }
#undef G1FLT
#undef G1ACC
    }
    __threadfence();
    grid.sync();

    // ================= Phase 4: gather2 + log_softmax (8 lanes/node) =================
    {
        int lane = t & 63;
        int gb = lane & 56;
#pragma unroll 1
        for (int idx = (int)blockIdx.x * 256 + t; idx < N * 8; idx += NBk * 256) {
            int node = idx >> 3, sub = idx & 7;
            int s = seg_start[node], cntc = counts[node];
            float dc = dinv[node];
            float2 bb = ((const float2*)b2)[sub];
            unsigned us = ((const unsigned*)(h2s + (size_t)node * F2))[sub];
            float ax = 0.f, ay = 0.f;

#define G2LOAD(n_) { int src = gb | min(n_, rem - 1); int r = __shfl(rl, src);              \
        w##n_ = ((const unsigned*)(h2s + (size_t)r * F2))[sub]; if (n_ >= rem) w##n_ = 0u; }

            int rl = 0;
            if (sub < min(cntc, 8)) rl = csr16[s + sub];
#pragma unroll 1
            for (int j0 = 0; j0 < cntc; j0 += 8) {
                int rem = min(cntc - j0, 8);
                int rlnext = 0;
                int j2 = j0 + 8;
                if (j2 < cntc && sub < cntc - j2) rlnext = csr16[s + j2 + sub];
                unsigned w0, w1, w2, w3, w4, w5, w6, w7;
                G2LOAD(0) G2LOAD(1) G2LOAD(2) G2LOAD(3)
                G2LOAD(4) G2LOAD(5) G2LOAD(6) G2LOAD(7)
                ax += ((blo(w0) + blo(w1)) + (blo(w2) + blo(w3))) +
                      ((blo(w4) + blo(w5)) + (blo(w6) + blo(w7)));
                ay += ((bhi(w0) + bhi(w1)) + (bhi(w2) + bhi(w3))) +
                      ((bhi(w4) + bhi(w5)) + (bhi(w6) + bhi(w7)));
                rl = rlnext;
            }
#undef G2LOAD
            ax += blo(us);
            ay += bhi(us);
            float v0 = fmaf(dc, ax, bb.x);
            float v1 = fmaf(dc, ay, bb.y);
            float mx = fmaxf(v0, v1);
#pragma unroll
            for (int mm = 1; mm < 8; mm <<= 1) mx = fmaxf(mx, __shfl_xor(mx, mm));
            float sm = expf(v0 - mx) + expf(v1 - mx);
#pragma unroll
            for (int mm = 1; mm < 8; mm <<= 1) sm += __shfl_xor(sm, mm);
            float lse = mx + logf(sm);
            float2 o;
            o.x = v0 - lse;
            o.y = v1 - lse;
            ((float2*)(out + (size_t)node * F2))[sub] = o;
        }
    }
}

extern "C" void kernel_launch(void* const* d_in, const int* in_sizes, int n_in,
                              void* d_out, int out_size, void* d_ws, size_t ws_size,
                              hipStream_t stream) {
    const float* x  = (const float*)d_in[0];
    const int*   ei = (const int*)d_in[1];
    const float* W1 = (const float*)d_in[2];
    const float* b1 = (const float*)d_in[3];
    const float* W2 = (const float*)d_in[4];
    const float* b2 = (const float*)d_in[5];
    const int* rowp = ei;
    const int* colp = ei + E;

    char* ws = (char*)d_ws;
    unsigned* P2        = (unsigned*)ws; ws += (size_t)SBLK * CHUNK * 4;    // 3.2 MB
    int*      cnt_g     = (int*)ws;      ws += (size_t)NBUCKET * SBLK * 4;  // 306 KB
    int*      loff_g    = (int*)ws;      ws += (size_t)NBUCKET * SBLK * 4;  // 306 KB
    ushort_t* csr16     = (ushort_t*)ws; ws += (size_t)NBUCKET * CAP * 2;   // 2.4 MB
    int*      seg_start = (int*)ws;      ws += (size_t)N * 4;
    int*      counts    = (int*)ws;      ws += (size_t)N * 4;
    float*    dinvp     = (float*)ws;    ws += (size_t)N * 4;
    uchar_t*  h1q       = (uchar_t*)ws;  ws += (size_t)N * F1;              // 6.4 MB
    ushort_t* h2s       = (ushort_t*)ws; ws += (size_t)N * F2 * 2;          // 1.6 MB
    float*    outp      = (float*)d_out;

    static int NB = 0;
    if (NB == 0) {
        int mbs = 0;
        (void)hipOccupancyMaxActiveBlocksPerMultiprocessor(&mbs, k_mega, 256, 0);
        if (mbs < 1) mbs = 1;
        long nb = (long)mbs * 256;   // 256 CUs on MI355X
        NB = (int)(nb > 1024 ? 1024 : nb);
        if (NB < 256) NB = 256;
    }

    void* args[] = { (void*)&rowp, (void*)&colp, (void*)&x, (void*)&W1, (void*)&b1,
                     (void*)&W2, (void*)&b2, (void*)&P2, (void*)&cnt_g, (void*)&loff_g,
                     (void*)&csr16, (void*)&seg_start, (void*)&counts, (void*)&dinvp,
                     (void*)&h1q, (void*)&h2s, (void*)&outp };
    (void)hipLaunchCooperativeKernel((const void*)k_mega, dim3(NB), dim3(256),
                                     args, 0, stream);
}

// Round 9
// 145.631 us; speedup vs baseline: 3.6356x; 2.6119x over previous
//
#include <hip/hip_runtime.h>
#include <math.h>

constexpr int N  = 50000;
constexpr int E  = 800000;
constexpr int F1 = 128;
constexpr int F2 = 16;
constexpr int BSHIFT  = 8;                        // 256-node buckets
constexpr int NBUCKET = (N + 255) >> BSHIFT;      // 196
constexpr int CHUNK   = 2048;                     // edges per scatter chunk
constexpr int CAP     = 6144;                     // per-bucket capacity
constexpr int SBLK    = (E + CHUNK - 1) / CHUNK;  // 391 scatter chunks
constexpr int GBLK    = 391;                      // gemm1-role blocks (2 x 64-row tiles)

typedef unsigned short ushort_t;
typedef unsigned char  uchar_t;
typedef __bf16 bf16x8 __attribute__((ext_vector_type(8)));
typedef float  f32x4  __attribute__((ext_vector_type(4)));

static __device__ __forceinline__ float blo(unsigned u) { return __uint_as_float(u << 16); }
static __device__ __forceinline__ float bhi(unsigned u) { return __uint_as_float(u & 0xffff0000u); }
static __device__ __forceinline__ ushort_t to_bf(float f) { __bf16 h = (__bf16)f; return *(ushort_t*)&h; }
static __device__ __forceinline__ uchar_t to_fp8(float f) {
    return (uchar_t)(__builtin_amdgcn_cvt_pk_fp8_f32(f, f, 0, false) & 0xff);
}
template <int S>
static __device__ __forceinline__ float cf8(unsigned u) {
    return __builtin_amdgcn_cvt_f32_fp8(u, S);
}

// ---------- K1: chunk scatter (atomic-free, role A) + GEMM1 x@W1 -> fp8 (role B) ----------
// role A: LDS histogram -> scan -> LDS bucket-sort -> write P2 block-contiguous (fully
//         coalesced) + per-(bucket,chunk) cnt/loff tables. No global atomics, no memset.
// role B: h1q = fp8(x @ W1), unscaled (dinv applied per-edge in K3).
__global__ __launch_bounds__(256) void k_scatterP_gemm1(const int* __restrict__ row,
                                                        const int* __restrict__ col,
                                                        unsigned* __restrict__ P2,
                                                        int* __restrict__ cnt_g,
                                                        int* __restrict__ loff_g,
                                                        const float* __restrict__ x,
                                                        const float* __restrict__ W1,
                                                        uchar_t* __restrict__ h1q) {
    __shared__ __align__(16) char smem[F1 * 136 * 2];  // 34.8 KB (gemm role Wl)
    int t = threadIdx.x;

    if (blockIdx.x < SBLK) {            // ---- scatter role: one chunk per block ----
        int* hist = (int*)smem;                  // [256]
        int* lcur = hist + 256;                  // [256]
        int* wtot = lcur + 256;                  // [8]
        unsigned* eb = (unsigned*)(wtot + 8);    // [2048]
        int j = blockIdx.x;
        int base = j * CHUNK;
        hist[t] = 0;
        __syncthreads();
        int ce[CHUNK / 256];
#pragma unroll
        for (int i = 0; i < CHUNK / 256; ++i) {
            int e = base + i * 256 + t;
            ce[i] = (e < E) ? col[e] : -1;
            if (ce[i] >= 0) atomicAdd(&hist[ce[i] >> BSHIFT], 1);
        }
        __syncthreads();
        {   // 256-thread exclusive scan
            int lane = t & 63, wid = t >> 6;
            int v = hist[t];
            int incl = v;
#pragma unroll
            for (int d = 1; d < 64; d <<= 1) {
                int u = __shfl_up(incl, d, 64);
                if (lane >= d) incl += u;
            }
            if (lane == 63) wtot[wid] = incl;
            __syncthreads();
            int wb = 0;
            for (int w = 0; w < wid; ++w) wb += wtot[w];
            int ex = wb + incl - v;
            lcur[t] = ex;
            if (t < NBUCKET) { cnt_g[t * SBLK + j] = v; loff_g[t * SBLK + j] = ex; }
        }
        __syncthreads();
#pragma unroll
        for (int i = 0; i < CHUNK / 256; ++i) {   // LDS bucket-sort
            int e = base + i * 256 + t;
            if (ce[i] >= 0) {
                int pos = atomicAdd(&lcur[ce[i] >> BSHIFT], 1);
                eb[pos] = ((unsigned)row[e] << BSHIFT) | (unsigned)(ce[i] & 255);
            }
        }
        __syncthreads();
        int total = min(CHUNK, E - base);
#pragma unroll
        for (int i = 0; i < CHUNK / 256; ++i) {   // block-contiguous, fully coalesced
            int k = i * 256 + t;
            if (k < total) P2[base + k] = eb[k];
        }
        return;
    }

    // ---- gemm1 role ----
    ushort_t* Wl = (ushort_t*)smem;              // [F1*136] bf16 W1^T
    int gb = blockIdx.x - SBLK;
    {   // W1[k][n] f32 -> Wl[n][k] bf16. Global reads coalesced (lane = n).
        int n = t & 127, kh = t >> 7;
#pragma unroll
        for (int j = 0; j < 8; ++j) {
            int k0 = (kh * 8 + j) * 8;
            bf16x8 w;
#pragma unroll
            for (int i2 = 0; i2 < 8; ++i2) w[i2] = (__bf16)W1[(k0 + i2) * F1 + n];
            *(bf16x8*)&Wl[n * 136 + k0] = w;
        }
    }
    __syncthreads();

    int lane = t & 63, wv = t >> 6;
    int quad = lane >> 4, l15 = lane & 15;
#pragma unroll 1
    for (int tile = gb * 2; tile < gb * 2 + 2; ++tile) {
        int arow = tile * 64 + wv * 16 + l15;
        int rclamp = min(arow, N - 1);
        f32x4 acc[8] = {};
#pragma unroll
        for (int kk = 0; kk < 4; ++kk) {
            int k0 = kk * 32 + quad * 8;
            const float* xp = x + (size_t)rclamp * F1 + k0;
            float4 u0 = *(const float4*)xp;
            float4 u1 = *(const float4*)(xp + 4);
            bf16x8 a;
            a[0] = (__bf16)u0.x; a[1] = (__bf16)u0.y; a[2] = (__bf16)u0.z; a[3] = (__bf16)u0.w;
            a[4] = (__bf16)u1.x; a[5] = (__bf16)u1.y; a[6] = (__bf16)u1.z; a[7] = (__bf16)u1.w;
#pragma unroll
            for (int ct = 0; ct < 8; ++ct) {
                bf16x8 bfr = *(const bf16x8*)&Wl[(ct * 16 + l15) * 136 + k0];
                acc[ct] = __builtin_amdgcn_mfma_f32_16x16x32_bf16(a, bfr, acc[ct], 0, 0, 0);
            }
        }
        int orow0 = tile * 64 + wv * 16 + quad * 4;
#pragma unroll
        for (int r = 0; r < 4; ++r) {
            int orow = orow0 + r;
            if (orow < N) {
#pragma unroll
                for (int ct = 0; ct < 8; ++ct)
                    h1q[(size_t)orow * F1 + ct * 16 + l15] = to_fp8(acc[ct][r]);
            }
        }
    }
}

// ---------- K2: per-bucket finalize from chunk tables (512 thr) ----------
// Scan 391 per-chunk counts -> gather bucket's edges (binary search) -> histogram ->
// seg_start/counts/dinv + csr16. Replaces the cursor-based binFinal (no memset needed).
__global__ __launch_bounds__(512) void k_binFinal(const unsigned* __restrict__ P2,
                                                  const int* __restrict__ cnt_g,
                                                  const int* __restrict__ loff_g,
                                                  ushort_t* __restrict__ csr16,
                                                  int* __restrict__ seg_start,
                                                  int* __restrict__ counts,
                                                  float* __restrict__ dinv) {
    __shared__ int cS[SBLK];
    __shared__ int oS[SBLK];
    __shared__ int baseS[SBLK];
    __shared__ int wtot[8];
    __shared__ int cnt[256];
    __shared__ int cur[256];
    __shared__ unsigned eb2[CAP];
    int t = threadIdx.x;
    int b = blockIdx.x;
    int lo = b << BSHIFT;
    if (t < SBLK) { cS[t] = cnt_g[b * SBLK + t]; oS[t] = loff_g[b * SBLK + t]; }
    if (t < 256) cnt[t] = 0;
    __syncthreads();
    int m;
    {   // 512-thread exclusive scan over chunk counts
        int lane = t & 63, wid = t >> 6;
        int v = (t < SBLK) ? cS[t] : 0;
        int incl = v;
#pragma unroll
        for (int d = 1; d < 64; d <<= 1) {
            int u = __shfl_up(incl, d, 64);
            if (lane >= d) incl += u;
        }
        if (lane == 63) wtot[wid] = incl;
        __syncthreads();
        int wb = 0;
        for (int w = 0; w < wid; ++w) wb += wtot[w];
        m = 0;
#pragma unroll
        for (int w = 0; w < 8; ++w) m += wtot[w];
        if (t < SBLK) baseS[t] = wb + incl - v;
    }
    __syncthreads();
    for (int k = t; k < m; k += 512) {   // gather + dest histogram
        int lo2 = 0, hi2 = SBLK - 1;
        while (lo2 < hi2) {
            int mid = (lo2 + hi2 + 1) >> 1;
            if (baseS[mid] <= k) lo2 = mid; else hi2 = mid - 1;
        }
        unsigned u = P2[lo2 * CHUNK + oS[lo2] + (k - baseS[lo2])];
        eb2[k] = u;
        atomicAdd(&cnt[u & 255], 1);
    }
    __syncthreads();
    {   // scan node histogram -> seg_start/counts/dinv
        int lane = t & 63, wid = t >> 6;
        int v = (t < 256) ? cnt[t] : 0;
        int incl = v;
#pragma unroll
        for (int d = 1; d < 64; d <<= 1) {
            int u = __shfl_up(incl, d, 64);
            if (lane >= d) incl += u;
        }
        if (lane == 63) wtot[wid] = incl;
        __syncthreads();
        int wb = 0;
        for (int w = 0; w < wid; ++w) wb += wtot[w];
        if (t < 256) {
            int o = b * CAP + wb + incl - v;   // csr16 mirrors padded bucket layout
            cur[t] = o;
            if (lo + t < N) {
                seg_start[lo + t] = o;
                counts[lo + t]    = v;
                dinv[lo + t]      = rsqrtf((float)v + 1.f);
            }
        }
    }
    __syncthreads();
    for (int k = t; k < m; k += 512) {
        unsigned u = eb2[k];
        int pos = atomicAdd(&cur[u & 255], 1);
        csr16[pos] = (ushort_t)(u >> BSHIFT);
    }
}

// ---------- K3: gather1 (4 chains/wave, chunk-pipelined) + fused GEMM2 ----------
__global__ __launch_bounds__(256) void k_gather1_gemm2(const uchar_t* __restrict__ h1q,
                                                       const int* __restrict__ seg_start,
                                                       const int* __restrict__ counts,
                                                       const ushort_t* __restrict__ csr16,
                                                       const float* __restrict__ dinv,
                                                       const float* __restrict__ W2,
                                                       const float* __restrict__ b1,
                                                       ushort_t* __restrict__ h2s) {
    __shared__ __align__(16) ushort_t W2l[F2 * 136];  // W2^T bf16 [n][k]
    __shared__ __align__(16) ushort_t T[16 * 136];    // 16 h1r rows, bf16
    __shared__ float dv[16];
    int t = threadIdx.x;
    for (int i = t; i < F1 * F2; i += 256) {   // W2 [128][16] f32 -> W2l[n][k]
        int k = i >> 4, n = i & 15;
        W2l[n * 136 + k] = to_bf(W2[i]);
    }
    int lane = t & 63, wv = t >> 6;
    int g = lane >> 4, l15 = lane & 15;
    int gbase = lane & 48;                 // g << 4
    int nl = wv * 4 + g;
    int c = blockIdx.x * 16 + nl;
    int cl = min(c, N - 1);

    float dc = 0.f;
    int s = seg_start[cl];
    int cnt = 0;
    if (c < N) { dc = dinv[c]; cnt = counts[c]; }
    uint2 wsf = *(const uint2*)(h1q + ((size_t)cl << 7) + (l15 << 3));
    float4 bL = ((const float4*)b1)[l15 * 2];
    float4 bH = ((const float4*)b1)[l15 * 2 + 1];
    int mcnt = cnt;
    mcnt = max(mcnt, __shfl_xor(mcnt, 16));
    mcnt = max(mcnt, __shfl_xor(mcnt, 32));

    float a0 = 0.f, a1 = 0.f, a2 = 0.f, a3 = 0.f;
    float a4 = 0.f, a5 = 0.f, a6 = 0.f, a7 = 0.f;

#define G1FLT(j_, jb_) { unsigned u = __shfl(pk, gbase + (jb_) + (j_));                     \
        e##j_ = __uint_as_float(u & 0xffff0000u);                                           \
        w##j_ = *(const uint2*)(h1q + ((size_t)(u & 0xffffu) << 7) + (l15 << 3)); }
#define G1ACC(j_) {                                                                         \
        a0 = fmaf(e##j_, cf8<0>(w##j_.x), a0); a1 = fmaf(e##j_, cf8<1>(w##j_.x), a1);       \
        a2 = fmaf(e##j_, cf8<2>(w##j_.x), a2); a3 = fmaf(e##j_, cf8<3>(w##j_.x), a3);       \
        a4 = fmaf(e##j_, cf8<0>(w##j_.y), a4); a5 = fmaf(e##j_, cf8<1>(w##j_.y), a5);       \
        a6 = fmaf(e##j_, cf8<2>(w##j_.y), a6); a7 = fmaf(e##j_, cf8<3>(w##j_.y), a7); }

    unsigned pk = 0;
    {   int k = l15;
        if (k < cnt) {
            int r = csr16[s + k];
            pk = ((unsigned)to_bf(dinv[r]) << 16) | (unsigned)r;
        }
    }
#pragma unroll 1
    for (int k0 = 0; k0 < mcnt; k0 += 16) {
        unsigned pknext = 0;
        {   int k = k0 + 16 + l15;   // next chunk's index+weight, issued early
            if (k < cnt) {
                int r = csr16[s + k];
                pknext = ((unsigned)to_bf(dinv[r]) << 16) | (unsigned)r;
            }
        }
        {   // flights 0..7
            uint2 w0, w1, w2, w3, w4, w5, w6, w7;
            float e0, e1, e2, e3, e4, e5, e6, e7;
            G1FLT(0, 0) G1FLT(1, 0) G1FLT(2, 0) G1FLT(3, 0)
            G1FLT(4, 0) G1FLT(5, 0) G1FLT(6, 0) G1FLT(7, 0)
            G1ACC(0) G1ACC(1) G1ACC(2) G1ACC(3)
            G1ACC(4) G1ACC(5) G1ACC(6) G1ACC(7)
        }
        if (k0 + 8 < mcnt) {   // flights 8..15
            uint2 w0, w1, w2, w3, w4, w5, w6, w7;
            float e0, e1, e2, e3, e4, e5, e6, e7;
            G1FLT(0, 8) G1FLT(1, 8) G1FLT(2, 8) G1FLT(3, 8)
            G1FLT(4, 8) G1FLT(5, 8) G1FLT(6, 8) G1FLT(7, 8)
            G1ACC(0) G1ACC(1) G1ACC(2) G1ACC(3)
            G1ACC(4) G1ACC(5) G1ACC(6) G1ACC(7)
        }
        pk = pknext;
    }
#undef G1FLT
#undef G1ACC

    {   // self term + bias + relu + pack -> T
        a0 = fmaf(dc, cf8<0>(wsf.x), a0); a1 = fmaf(dc, cf8<1>(wsf.x), a1);
        a2 = fmaf(dc, cf8<2>(wsf.x), a2); a3 = fmaf(dc, cf8<3>(wsf.x), a3);
        a4 = fmaf(dc, cf8<0>(wsf.y), a4); a5 = fmaf(dc, cf8<1>(wsf.y), a5);
        a6 = fmaf(dc, cf8<2>(wsf.y), a6); a7 = fmaf(dc, cf8<3>(wsf.y), a7);
        a0 = fmaxf(fmaf(dc, a0, bL.x), 0.f); a1 = fmaxf(fmaf(dc, a1, bL.y), 0.f);
        a2 = fmaxf(fmaf(dc, a2, bL.z), 0.f); a3 = fmaxf(fmaf(dc, a3, bL.w), 0.f);
        a4 = fmaxf(fmaf(dc, a4, bH.x), 0.f); a5 = fmaxf(fmaf(dc, a5, bH.y), 0.f);
        a6 = fmaxf(fmaf(dc, a6, bH.z), 0.f); a7 = fmaxf(fmaf(dc, a7, bH.w), 0.f);
        uint4 pp;
        pp.x = (unsigned)to_bf(a0) | ((unsigned)to_bf(a1) << 16);
        pp.y = (unsigned)to_bf(a2) | ((unsigned)to_bf(a3) << 16);
        pp.z = (unsigned)to_bf(a4) | ((unsigned)to_bf(a5) << 16);
        pp.w = (unsigned)to_bf(a6) | ((unsigned)to_bf(a7) << 16);
        *(uint4*)&T[nl * 136 + (l15 << 3)] = pp;
        if (l15 == 0) dv[nl] = dc;
    }
    __syncthreads();

    if (wv == 0) {   // 16x16 tile: T(16x128) @ W2l^T(128x16)
        int quad = lane >> 4;
        f32x4 acc = {};
#pragma unroll
        for (int kk = 0; kk < 4; ++kk) {
            int k0 = kk * 32 + quad * 8;
            bf16x8 a = *(const bf16x8*)&T[l15 * 136 + k0];
            bf16x8 bfr = *(const bf16x8*)&W2l[l15 * 136 + k0];
            acc = __builtin_amdgcn_mfma_f32_16x16x32_bf16(a, bfr, acc, 0, 0, 0);
        }
#pragma unroll
        for (int r = 0; r < 4; ++r) {
            int rw = quad * 4 + r;
            int gn = blockIdx.x * 16 + rw;
            if (gn < N) h2s[(size_t)gn * F2 + l15] = to_bf(acc[r] * dv[rw]);
        }
    }
}

// ---------- K4: gather2 + log_softmax (8 lanes/node, chunk-pipelined) ----------
__global__ __launch_bounds__(256) void k_gather2(const ushort_t* __restrict__ h2s,
                                                 const int* __restrict__ seg_start,
                                                 const int* __restrict__ counts,
                                                 const ushort_t* __restrict__ csr16,
                                                 const float* __restrict__ dinv,
                                                 const float* __restrict__ b2,
                                                 float* __restrict__ out) {
    int idx = blockIdx.x * 256 + threadIdx.x;
    int node = idx >> 3, sub = idx & 7;
    if (node >= N) return;
    int lane = threadIdx.x & 63;
    int gb = lane & 56;
    int s = seg_start[node], cntc = counts[node];
    float dc = dinv[node];
    float2 bb = ((const float2*)b2)[sub];
    unsigned us = ((const unsigned*)(h2s + (size_t)node * F2))[sub];
    float ax = 0.f, ay = 0.f;

#define G2LOAD(n_) { int src = gb | min(n_, rem - 1); int r = __shfl(rl, src);              \
        w##n_ = ((const unsigned*)(h2s + (size_t)r * F2))[sub]; if (n_ >= rem) w##n_ = 0u; }

    int rl = 0;
    if (sub < min(cntc, 8)) rl = csr16[s + sub];
#pragma unroll 1
    for (int j0 = 0; j0 < cntc; j0 += 8) {
        int rem = min(cntc - j0, 8);
        int rlnext = 0;
        int j2 = j0 + 8;
        if (j2 < cntc && sub < cntc - j2) rlnext = csr16[s + j2 + sub];
        unsigned w0, w1, w2, w3, w4, w5, w6, w7;
        G2LOAD(0) G2LOAD(1) G2LOAD(2) G2LOAD(3)
        G2LOAD(4) G2LOAD(5) G2LOAD(6) G2LOAD(7)
        ax += ((blo(w0) + blo(w1)) + (blo(w2) + blo(w3))) +
              ((blo(w4) + blo(w5)) + (blo(w6) + blo(w7)));
        ay += ((bhi(w0) + bhi(w1)) + (bhi(w2) + bhi(w3))) +
              ((bhi(w4) + bhi(w5)) + (bhi(w6) + bhi(w7)));
        rl = rlnext;
    }
#undef G2LOAD
    ax += blo(us);
    ay += bhi(us);
    float v0 = fmaf(dc, ax, bb.x);
    float v1 = fmaf(dc, ay, bb.y);
    float mx = fmaxf(v0, v1);
#pragma unroll
    for (int m = 1; m < 8; m <<= 1) mx = fmaxf(mx, __shfl_xor(mx, m));
    float sm = expf(v0 - mx) + expf(v1 - mx);
#pragma unroll
    for (int m = 1; m < 8; m <<= 1) sm += __shfl_xor(sm, m);
    float lse = mx + logf(sm);
    float2 o;
    o.x = v0 - lse;
    o.y = v1 - lse;
    ((float2*)(out + (size_t)node * F2))[sub] = o;
}

extern "C" void kernel_launch(void* const* d_in, const int* in_sizes, int n_in,
                              void* d_out, int out_size, void* d_ws, size_t ws_size,
                              hipStream_t stream) {
    const float* x  = (const float*)d_in[0];
    const int*   ei = (const int*)d_in[1];
    const float* W1 = (const float*)d_in[2];
    const float* b1 = (const float*)d_in[3];
    const float* W2 = (const float*)d_in[4];
    const float* b2 = (const float*)d_in[5];
    const int* rowp = ei;
    const int* colp = ei + E;

    char* ws = (char*)d_ws;
    unsigned* P2        = (unsigned*)ws; ws += (size_t)SBLK * CHUNK * 4;    // 3.2 MB
    int*      cnt_g     = (int*)ws;      ws += (size_t)NBUCKET * SBLK * 4;  // 306 KB
    int*      loff_g    = (int*)ws;      ws += (size_t)NBUCKET * SBLK * 4;  // 306 KB
    ushort_t* csr16     = (ushort_t*)ws; ws += (size_t)NBUCKET * CAP * 2;   // 2.4 MB
    int*      seg_start = (int*)ws;      ws += (size_t)N * 4;
    int*      counts    = (int*)ws;      ws += (size_t)N * 4;
    float*    dinvp     = (float*)ws;    ws += (size_t)N * 4;
    uchar_t*  h1q       = (uchar_t*)ws;  ws += (size_t)N * F1;              // 6.4 MB
    ushort_t* h2s       = (ushort_t*)ws; ws += (size_t)N * F2 * 2;          // 1.6 MB

    k_scatterP_gemm1<<<SBLK + GBLK, 256, 0, stream>>>(rowp, colp, P2, cnt_g, loff_g,
                                                      x, W1, h1q);
    k_binFinal<<<NBUCKET, 512, 0, stream>>>(P2, cnt_g, loff_g, csr16, seg_start,
                                            counts, dinvp);
    k_gather1_gemm2<<<(N + 15) / 16, 256, 0, stream>>>(h1q, seg_start, counts, csr16,
                                                       dinvp, W2, b1, h2s);
    k_gather2<<<((size_t)N * 8 + 255) / 256, 256, 0, stream>>>(h2s, seg_start, counts, csr16,
                                                               dinvp, b2, (float*)d_out);
}

// Round 10
// 145.447 us; speedup vs baseline: 3.6402x; 1.0013x over previous
//
#include <hip/hip_runtime.h>
#include <math.h>

constexpr int N  = 50000;
constexpr int E  = 800000;
constexpr int F1 = 128;
constexpr int F2 = 16;
constexpr int BSHIFT  = 8;                        // 256-node buckets
constexpr int NBUCKET = (N + 255) >> BSHIFT;      // 196
constexpr int CHUNK   = 2048;                     // edges per scatter chunk
constexpr int CAP     = 6144;                     // per-bucket capacity
constexpr int SBLK    = (E + CHUNK - 1) / CHUNK;  // 391 scatter chunks
constexpr int GBLK    = 391;                      // gemm1-role blocks (2 x 64-row tiles)

typedef unsigned short ushort_t;
typedef unsigned char  uchar_t;
typedef __bf16 bf16x8 __attribute__((ext_vector_type(8)));
typedef float  f32x4  __attribute__((ext_vector_type(4)));

static __device__ __forceinline__ float blo(unsigned u) { return __uint_as_float(u << 16); }
static __device__ __forceinline__ float bhi(unsigned u) { return __uint_as_float(u & 0xffff0000u); }
static __device__ __forceinline__ ushort_t to_bf(float f) { __bf16 h = (__bf16)f; return *(ushort_t*)&h; }
static __device__ __forceinline__ uchar_t to_fp8(float f) {
    return (uchar_t)(__builtin_amdgcn_cvt_pk_fp8_f32(f, f, 0, false) & 0xff);
}
template <int S>
static __device__ __forceinline__ float cf8(unsigned u) {
    return __builtin_amdgcn_cvt_f32_fp8(u, S);
}

// ---------- K1: chunk scatter (atomic-free, role A) + GEMM1 x@W1 -> fp8 (role B) ----------
__global__ __launch_bounds__(256) void k_scatterP_gemm1(const int* __restrict__ row,
                                                        const int* __restrict__ col,
                                                        unsigned* __restrict__ P2,
                                                        int* __restrict__ cnt_g,
                                                        int* __restrict__ loff_g,
                                                        const float* __restrict__ x,
                                                        const float* __restrict__ W1,
                                                        uchar_t* __restrict__ h1q) {
    __shared__ __align__(16) char smem[F1 * 136 * 2];  // 34.8 KB (gemm role Wl)
    int t = threadIdx.x;

    if (blockIdx.x < SBLK) {            // ---- scatter role: one chunk per block ----
        int* hist = (int*)smem;                  // [256]
        int* lcur = hist + 256;                  // [256]
        int* wtot = lcur + 256;                  // [8]
        unsigned* eb = (unsigned*)(wtot + 8);    // [2048]
        int j = blockIdx.x;
        int base = j * CHUNK;
        hist[t] = 0;
        __syncthreads();
        int ce[CHUNK / 256];
#pragma unroll
        for (int i = 0; i < CHUNK / 256; ++i) {
            int e = base + i * 256 + t;
            ce[i] = (e < E) ? col[e] : -1;
            if (ce[i] >= 0) atomicAdd(&hist[ce[i] >> BSHIFT], 1);
        }
        __syncthreads();
        {   // 256-thread exclusive scan
            int lane = t & 63, wid = t >> 6;
            int v = hist[t];
            int incl = v;
#pragma unroll
            for (int d = 1; d < 64; d <<= 1) {
                int u = __shfl_up(incl, d, 64);
                if (lane >= d) incl += u;
            }
            if (lane == 63) wtot[wid] = incl;
            __syncthreads();
            int wb = 0;
            for (int w = 0; w < wid; ++w) wb += wtot[w];
            int ex = wb + incl - v;
            lcur[t] = ex;
            if (t < NBUCKET) { cnt_g[t * SBLK + j] = v; loff_g[t * SBLK + j] = ex; }
        }
        __syncthreads();
#pragma unroll
        for (int i = 0; i < CHUNK / 256; ++i) {   // LDS bucket-sort
            int e = base + i * 256 + t;
            if (ce[i] >= 0) {
                int pos = atomicAdd(&lcur[ce[i] >> BSHIFT], 1);
                eb[pos] = ((unsigned)row[e] << BSHIFT) | (unsigned)(ce[i] & 255);
            }
        }
        __syncthreads();
        int total = min(CHUNK, E - base);
#pragma unroll
        for (int i = 0; i < CHUNK / 256; ++i) {   // block-contiguous, fully coalesced
            int k = i * 256 + t;
            if (k < total) P2[base + k] = eb[k];
        }
        return;
    }

    // ---- gemm1 role ----
    ushort_t* Wl = (ushort_t*)smem;              // [F1*136] bf16 W1^T
    int gb = blockIdx.x - SBLK;
    {   // W1[k][n] f32 -> Wl[n][k] bf16. Global reads coalesced (lane = n).
        int n = t & 127, kh = t >> 7;
#pragma unroll
        for (int j = 0; j < 8; ++j) {
            int k0 = (kh * 8 + j) * 8;
            bf16x8 w;
#pragma unroll
            for (int i2 = 0; i2 < 8; ++i2) w[i2] = (__bf16)W1[(k0 + i2) * F1 + n];
            *(bf16x8*)&Wl[n * 136 + k0] = w;
        }
    }
    __syncthreads();

    int lane = t & 63, wv = t >> 6;
    int quad = lane >> 4, l15 = lane & 15;
#pragma unroll 1
    for (int tile = gb * 2; tile < gb * 2 + 2; ++tile) {
        int arow = tile * 64 + wv * 16 + l15;
        int rclamp = min(arow, N - 1);
        f32x4 acc[8] = {};
#pragma unroll
        for (int kk = 0; kk < 4; ++kk) {
            int k0 = kk * 32 + quad * 8;
            const float* xp = x + (size_t)rclamp * F1 + k0;
            float4 u0 = *(const float4*)xp;
            float4 u1 = *(const float4*)(xp + 4);
            bf16x8 a;
            a[0] = (__bf16)u0.x; a[1] = (__bf16)u0.y; a[2] = (__bf16)u0.z; a[3] = (__bf16)u0.w;
            a[4] = (__bf16)u1.x; a[5] = (__bf16)u1.y; a[6] = (__bf16)u1.z; a[7] = (__bf16)u1.w;
#pragma unroll
            for (int ct = 0; ct < 8; ++ct) {
                bf16x8 bfr = *(const bf16x8*)&Wl[(ct * 16 + l15) * 136 + k0];
                acc[ct] = __builtin_amdgcn_mfma_f32_16x16x32_bf16(a, bfr, acc[ct], 0, 0, 0);
            }
        }
        int orow0 = tile * 64 + wv * 16 + quad * 4;
#pragma unroll
        for (int r = 0; r < 4; ++r) {
            int orow = orow0 + r;
            if (orow < N) {
#pragma unroll
                for (int ct = 0; ct < 8; ++ct)
                    h1q[(size_t)orow * F1 + ct * 16 + l15] = to_fp8(acc[ct][r]);
            }
        }
    }
}

// ---------- K2: per-bucket finalize, chunk-major (1024 thr, no binary search) ----------
// Scan 391 per-chunk counts -> each wave copies whole chunk-segments into eb2 (direct
// addressing) + histogram -> node scan -> csr16 scatter.
__global__ __launch_bounds__(1024) void k_binFinal(const unsigned* __restrict__ P2,
                                                   const int* __restrict__ cnt_g,
                                                   const int* __restrict__ loff_g,
                                                   ushort_t* __restrict__ csr16,
                                                   int* __restrict__ seg_start,
                                                   int* __restrict__ counts,
                                                   float* __restrict__ dinv) {
    __shared__ int cS[SBLK];
    __shared__ int oS[SBLK];
    __shared__ int baseS[SBLK];
    __shared__ int wtot[16];
    __shared__ int cnt[256];
    __shared__ int cur[256];
    __shared__ unsigned eb2[CAP];
    int t = threadIdx.x;
    int b = blockIdx.x;
    int lo = b << BSHIFT;
    int lane = t & 63, wid = t >> 6;     // 16 waves
    if (t < SBLK) { cS[t] = cnt_g[b * SBLK + t]; oS[t] = loff_g[b * SBLK + t]; }
    if (t < 256) cnt[t] = 0;
    __syncthreads();
    int m;
    {   // exclusive scan over chunk counts (1024-padded)
        int v = (t < SBLK) ? cS[t] : 0;
        int incl = v;
#pragma unroll
        for (int d = 1; d < 64; d <<= 1) {
            int u = __shfl_up(incl, d, 64);
            if (lane >= d) incl += u;
        }
        if (lane == 63) wtot[wid] = incl;
        __syncthreads();
        int wb = 0;
        for (int w = 0; w < wid; ++w) wb += wtot[w];
        m = 0;
#pragma unroll
        for (int w = 0; w < 16; ++w) m += wtot[w];
        if (t < SBLK) baseS[t] = wb + incl - v;
    }
    __syncthreads();
    // chunk-major gather: wave wid handles chunks wid, wid+16, ... (no per-edge search)
    for (int j = wid; j < SBLK; j += 16) {
        int c = cS[j];
        int src = j * CHUNK + oS[j];
        int dst = baseS[j];
        for (int k = lane; k < c; k += 64) {
            unsigned u = P2[src + k];
            eb2[dst + k] = u;
            atomicAdd(&cnt[u & 255], 1);
        }
    }
    __syncthreads();
    {   // node histogram scan -> seg_start/counts/dinv
        int v = (t < 256) ? cnt[t] : 0;
        int incl = v;
#pragma unroll
        for (int d = 1; d < 64; d <<= 1) {
            int u = __shfl_up(incl, d, 64);
            if (lane >= d) incl += u;
        }
        if (lane == 63) wtot[wid] = incl;
        __syncthreads();
        int wb = 0;
        for (int w = 0; w < wid; ++w) wb += wtot[w];
        if (t < 256) {
            int o = b * CAP + wb + incl - v;   // csr16 mirrors padded bucket layout
            cur[t] = o;
            if (lo + t < N) {
                seg_start[lo + t] = o;
                counts[lo + t]    = v;
                dinv[lo + t]      = rsqrtf((float)v + 1.f);
            }
        }
    }
    __syncthreads();
    for (int k = t; k < m; k += 1024) {
        unsigned u = eb2[k];
        int pos = atomicAdd(&cur[u & 255], 1);
        csr16[pos] = (ushort_t)(u >> BSHIFT);
    }
}

// ---------- K3: gather1 (4 chains/wave, chunk-pipelined) + fused GEMM2 ----------
__global__ __launch_bounds__(256) void k_gather1_gemm2(const uchar_t* __restrict__ h1q,
                                                       const int* __restrict__ seg_start,
                                                       const int* __restrict__ counts,
                                                       const ushort_t* __restrict__ csr16,
                                                       const float* __restrict__ dinv,
                                                       const float* __restrict__ W2,
                                                       const float* __restrict__ b1,
                                                       ushort_t* __restrict__ h2s) {
    __shared__ __align__(16) ushort_t W2l[F2 * 136];  // W2^T bf16 [n][k]
    __shared__ __align__(16) ushort_t T[16 * 136];    // 16 h1r rows, bf16
    __shared__ float dv[16];
    int t = threadIdx.x;
    for (int i = t; i < F1 * F2; i += 256) {   // W2 [128][16] f32 -> W2l[n][k]
        int k = i >> 4, n = i & 15;
        W2l[n * 136 + k] = to_bf(W2[i]);
    }
    int lane = t & 63, wv = t >> 6;
    int g = lane >> 4, l15 = lane & 15;
    int gbase = lane & 48;                 // g << 4
    int nl = wv * 4 + g;
    int c = blockIdx.x * 16 + nl;
    int cl = min(c, N - 1);

    float dc = 0.f;
    int s = seg_start[cl];
    int cnt = 0;
    if (c < N) { dc = dinv[c]; cnt = counts[c]; }
    uint2 wsf = *(const uint2*)(h1q + ((size_t)cl << 7) + (l15 << 3));
    float4 bL = ((const float4*)b1)[l15 * 2];
    float4 bH = ((const float4*)b1)[l15 * 2 + 1];
    int mcnt = cnt;
    mcnt = max(mcnt, __shfl_xor(mcnt, 16));
    mcnt = max(mcnt, __shfl_xor(mcnt, 32));

    float a0 = 0.f, a1 = 0.f, a2 = 0.f, a3 = 0.f;
    float a4 = 0.f, a5 = 0.f, a6 = 0.f, a7 = 0.f;

#define G1FLT(j_, jb_) { unsigned u = __shfl(pk, gbase + (jb_) + (j_));                     \
        e##j_ = __uint_as_float(u & 0xffff0000u);                                           \
        w##j_ = *(const uint2*)(h1q + ((size_t)(u & 0xffffu) << 7) + (l15 << 3)); }
#define G1ACC(j_) {                                                                         \
        a0 = fmaf(e##j_, cf8<0>(w##j_.x), a0); a1 = fmaf(e##j_, cf8<1>(w##j_.x), a1);       \
        a2 = fmaf(e##j_, cf8<2>(w##j_.x), a2); a3 = fmaf(e##j_, cf8<3>(w##j_.x), a3);       \
        a4 = fmaf(e##j_, cf8<0>(w##j_.y), a4); a5 = fmaf(e##j_, cf8<1>(w##j_.y), a5);       \
        a6 = fmaf(e##j_, cf8<2>(w##j_.y), a6); a7 = fmaf(e##j_, cf8<3>(w##j_.y), a7); }

    unsigned pk = 0;
    {   int k = l15;
        if (k < cnt) {
            int r = csr16[s + k];
            pk = ((unsigned)to_bf(dinv[r]) << 16) | (unsigned)r;
        }
    }
#pragma unroll 1
    for (int k0 = 0; k0 < mcnt; k0 += 16) {
        unsigned pknext = 0;
        {   int k = k0 + 16 + l15;   // next chunk's index+weight, issued early
            if (k < cnt) {
                int r = csr16[s + k];
                pknext = ((unsigned)to_bf(dinv[r]) << 16) | (unsigned)r;
            }
        }
        {   // flights 0..7
            uint2 w0, w1, w2, w3, w4, w5, w6, w7;
            float e0, e1, e2, e3, e4, e5, e6, e7;
            G1FLT(0, 0) G1FLT(1, 0) G1FLT(2, 0) G1FLT(3, 0)
            G1FLT(4, 0) G1FLT(5, 0) G1FLT(6, 0) G1FLT(7, 0)
            G1ACC(0) G1ACC(1) G1ACC(2) G1ACC(3)
            G1ACC(4) G1ACC(5) G1ACC(6) G1ACC(7)
        }
        if (k0 + 8 < mcnt) {   // flights 8..15
            uint2 w0, w1, w2, w3, w4, w5, w6, w7;
            float e0, e1, e2, e3, e4, e5, e6, e7;
            G1FLT(0, 8) G1FLT(1, 8) G1FLT(2, 8) G1FLT(3, 8)
            G1FLT(4, 8) G1FLT(5, 8) G1FLT(6, 8) G1FLT(7, 8)
            G1ACC(0) G1ACC(1) G1ACC(2) G1ACC(3)
            G1ACC(4) G1ACC(5) G1ACC(6) G1ACC(7)
        }
        pk = pknext;
    }
#undef G1FLT
#undef G1ACC

    {   // self term + bias + relu + pack -> T
        a0 = fmaf(dc, cf8<0>(wsf.x), a0); a1 = fmaf(dc, cf8<1>(wsf.x), a1);
        a2 = fmaf(dc, cf8<2>(wsf.x), a2); a3 = fmaf(dc, cf8<3>(wsf.x), a3);
        a4 = fmaf(dc, cf8<0>(wsf.y), a4); a5 = fmaf(dc, cf8<1>(wsf.y), a5);
        a6 = fmaf(dc, cf8<2>(wsf.y), a6); a7 = fmaf(dc, cf8<3>(wsf.y), a7);
        a0 = fmaxf(fmaf(dc, a0, bL.x), 0.f); a1 = fmaxf(fmaf(dc, a1, bL.y), 0.f);
        a2 = fmaxf(fmaf(dc, a2, bL.z), 0.f); a3 = fmaxf(fmaf(dc, a3, bL.w), 0.f);
        a4 = fmaxf(fmaf(dc, a4, bH.x), 0.f); a5 = fmaxf(fmaf(dc, a5, bH.y), 0.f);
        a6 = fmaxf(fmaf(dc, a6, bH.z), 0.f); a7 = fmaxf(fmaf(dc, a7, bH.w), 0.f);
        uint4 pp;
        pp.x = (unsigned)to_bf(a0) | ((unsigned)to_bf(a1) << 16);
        pp.y = (unsigned)to_bf(a2) | ((unsigned)to_bf(a3) << 16);
        pp.z = (unsigned)to_bf(a4) | ((unsigned)to_bf(a5) << 16);
        pp.w = (unsigned)to_bf(a6) | ((unsigned)to_bf(a7) << 16);
        *(uint4*)&T[nl * 136 + (l15 << 3)] = pp;
        if (l15 == 0) dv[nl] = dc;
    }
    __syncthreads();

    if (wv == 0) {   // 16x16 tile: T(16x128) @ W2l^T(128x16)
        int quad = lane >> 4;
        f32x4 acc = {};
#pragma unroll
        for (int kk = 0; kk < 4; ++kk) {
            int k0 = kk * 32 + quad * 8;
            bf16x8 a = *(const bf16x8*)&T[l15 * 136 + k0];
            bf16x8 bfr = *(const bf16x8*)&W2l[l15 * 136 + k0];
            acc = __builtin_amdgcn_mfma_f32_16x16x32_bf16(a, bfr, acc, 0, 0, 0);
        }
#pragma unroll
        for (int r = 0; r < 4; ++r) {
            int rw = quad * 4 + r;
            int gn = blockIdx.x * 16 + rw;
            if (gn < N) h2s[(size_t)gn * F2 + l15] = to_bf(acc[r] * dv[rw]);
        }
    }
}

// ---------- K4: gather2 + log_softmax (8 lanes/node, 16-deep pipeline) ----------
__global__ __launch_bounds__(256) void k_gather2(const ushort_t* __restrict__ h2s,
                                                 const int* __restrict__ seg_start,
                                                 const int* __restrict__ counts,
                                                 const ushort_t* __restrict__ csr16,
                                                 const float* __restrict__ dinv,
                                                 const float* __restrict__ b2,
                                                 float* __restrict__ out) {
    int idx = blockIdx.x * 256 + threadIdx.x;
    int node = idx >> 3, sub = idx & 7;
    if (node >= N) return;
    int lane = threadIdx.x & 63;
    int gb = lane & 56;
    int s = seg_start[node], cntc = counts[node];
    float dc = dinv[node];
    float2 bb = ((const float2*)b2)[sub];
    unsigned us = ((const unsigned*)(h2s + (size_t)node * F2))[sub];
    float ax = 0.f, ay = 0.f;

#define G2L0(n_) { int src = gb | (n_); int r = __shfl(rl0, src);                           \
        w##n_ = ((const unsigned*)(h2s + (size_t)r * F2))[sub]; if ((n_) >= rem) w##n_ = 0u; }
#define G2L1(n_) { int src = gb | ((n_) - 8); int r = __shfl(rl1, src);                     \
        w##n_ = ((const unsigned*)(h2s + (size_t)r * F2))[sub]; if ((n_) >= rem) w##n_ = 0u; }

    int rl0 = 0, rl1 = 0;
    if (sub < cntc) rl0 = csr16[s + sub];
    if (8 + sub < cntc) rl1 = csr16[s + 8 + sub];
#pragma unroll 1
    for (int j0 = 0; j0 < cntc; j0 += 16) {
        int rem = cntc - j0;
        int rn0 = 0, rn1 = 0;
        int j2 = j0 + 16;
        if (j2 + sub < cntc) rn0 = csr16[s + j2 + sub];
        if (j2 + 8 + sub < cntc) rn1 = csr16[s + j2 + 8 + sub];
        unsigned w0, w1, w2, w3, w4, w5, w6, w7, w8, w9, w10, w11, w12, w13, w14, w15;
        G2L0(0) G2L0(1) G2L0(2) G2L0(3) G2L0(4) G2L0(5) G2L0(6) G2L0(7)
        G2L1(8) G2L1(9) G2L1(10) G2L1(11) G2L1(12) G2L1(13) G2L1(14) G2L1(15)
        ax += (((blo(w0) + blo(w1)) + (blo(w2) + blo(w3))) +
               ((blo(w4) + blo(w5)) + (blo(w6) + blo(w7)))) +
              (((blo(w8) + blo(w9)) + (blo(w10) + blo(w11))) +
               ((blo(w12) + blo(w13)) + (blo(w14) + blo(w15))));
        ay += (((bhi(w0) + bhi(w1)) + (bhi(w2) + bhi(w3))) +
               ((bhi(w4) + bhi(w5)) + (bhi(w6) + bhi(w7)))) +
              (((bhi(w8) + bhi(w9)) + (bhi(w10) + bhi(w11))) +
               ((bhi(w12) + bhi(w13)) + (bhi(w14) + bhi(w15))));
        rl0 = rn0; rl1 = rn1;
    }
#undef G2L0
#undef G2L1
    ax += blo(us);
    ay += bhi(us);
    float v0 = fmaf(dc, ax, bb.x);
    float v1 = fmaf(dc, ay, bb.y);
    float mx = fmaxf(v0, v1);
#pragma unroll
    for (int m = 1; m < 8; m <<= 1) mx = fmaxf(mx, __shfl_xor(mx, m));
    float sm = expf(v0 - mx) + expf(v1 - mx);
#pragma unroll
    for (int m = 1; m < 8; m <<= 1) sm += __shfl_xor(sm, m);
    float lse = mx + logf(sm);
    float2 o;
    o.x = v0 - lse;
    o.y = v1 - lse;
    ((float2*)(out + (size_t)node * F2))[sub] = o;
}

extern "C" void kernel_launch(void* const* d_in, const int* in_sizes, int n_in,
                              void* d_out, int out_size, void* d_ws, size_t ws_size,
                              hipStream_t stream) {
    const float* x  = (const float*)d_in[0];
    const int*   ei = (const int*)d_in[1];
    const float* W1 = (const float*)d_in[2];
    const float* b1 = (const float*)d_in[3];
    const float* W2 = (const float*)d_in[4];
    const float* b2 = (const float*)d_in[5];
    const int* rowp = ei;
    const int* colp = ei + E;

    char* ws = (char*)d_ws;
    unsigned* P2        = (unsigned*)ws; ws += (size_t)SBLK * CHUNK * 4;    // 3.2 MB
    int*      cnt_g     = (int*)ws;      ws += (size_t)NBUCKET * SBLK * 4;  // 306 KB
    int*      loff_g    = (int*)ws;      ws += (size_t)NBUCKET * SBLK * 4;  // 306 KB
    ushort_t* csr16     = (ushort_t*)ws; ws += (size_t)NBUCKET * CAP * 2;   // 2.4 MB
    int*      seg_start = (int*)ws;      ws += (size_t)N * 4;
    int*      counts    = (int*)ws;      ws += (size_t)N * 4;
    float*    dinvp     = (float*)ws;    ws += (size_t)N * 4;
    uchar_t*  h1q       = (uchar_t*)ws;  ws += (size_t)N * F1;              // 6.4 MB
    ushort_t* h2s       = (ushort_t*)ws; ws += (size_t)N * F2 * 2;          // 1.6 MB

    k_scatterP_gemm1<<<SBLK + GBLK, 256, 0, stream>>>(rowp, colp, P2, cnt_g, loff_g,
                                                      x, W1, h1q);
    k_binFinal<<<NBUCKET, 1024, 0, stream>>>(P2, cnt_g, loff_g, csr16, seg_start,
                                             counts, dinvp);
    k_gather1_gemm2<<<(N + 15) / 16, 256, 0, stream>>>(h1q, seg_start, counts, csr16,
                                                       dinvp, W2, b1, h2s);
    k_gather2<<<((size_t)N * 8 + 255) / 256, 256, 0, stream>>>(h2s, seg_start, counts, csr16,
                                                               dinvp, b2, (float*)d_out);
}